// Round 3
// baseline (110.040 us; speedup 1.0000x reference)
//
#include <hip/hip_runtime.h>
#include <hip/hip_bf16.h>

// Dynamic conv2d: B=16, C_in=64, H=W=128, C_out=64, K=5 kernels, ks=3, pad=1.
// R3: LDS-free implicit-GEMM conv (B fragments straight from L1/L2-resident xT),
// no barriers, higher occupancy; coalesced transpose.

typedef __attribute__((ext_vector_type(8))) __bf16 bf16x8;
typedef __attribute__((ext_vector_type(16))) float f32x16;
typedef __attribute__((ext_vector_type(4))) unsigned int u32x4;

#define NB 16
#define CI 64
#define CO 64
#define HH 128
#define WW 128
#define KBANK 5
#define KDIM 576            // CI * 9, k = tap*64 + ci

__device__ __forceinline__ short f2bf(float f) {
    __hip_bfloat16 h = __float2bfloat16(f);
    short s;
    __builtin_memcpy(&s, &h, 2);
    return s;
}

// ---------------- kernel 1: aggregate weights + bias ----------------
__global__ void prep_kernel(const float* __restrict__ weights,
                            const float* __restrict__ Wbank,
                            const float* __restrict__ bbank,
                            short* __restrict__ aggw,
                            float* __restrict__ aggb) {
    int idx = blockIdx.x * 256 + threadIdx.x;          // < 16*64*576 = 589824
    int b  = idx / (CO * KDIM);
    int r  = idx - b * (CO * KDIM);
    int co = r / KDIM;
    int k  = r - co * KDIM;
    int tap = k >> 6;          // 0..8
    int ci  = k & 63;
    float s = 0.f;
#pragma unroll
    for (int kk = 0; kk < KBANK; ++kk)
        s += weights[b * KBANK + kk] * Wbank[((kk * CO + co) * CI + ci) * 9 + tap];
    aggw[idx] = f2bf(s);
    if (k == 0) {
        float sb = 0.f;
#pragma unroll
        for (int kk = 0; kk < KBANK; ++kk)
            sb += weights[b * KBANK + kk] * bbank[kk * CO + co];
        aggb[b * CO + co] = sb;
    }
}

// ---------------- kernel 2: x NCHW fp32 -> xT [b][h][w][ci] bf16 ----------------
// w is the lane index -> each of the 8 loads is a fully-coalesced 256B/wave read.
__global__ void transpose_kernel(const float* __restrict__ x, short* __restrict__ xT) {
    int idx = blockIdx.x * 256 + threadIdx.x;          // 2^21 threads
    int w = idx & 127;
    int c = (idx >> 7) & 7;        // ci chunk
    int h = (idx >> 10) & 127;
    int b = idx >> 17;
    union { short s[8]; u32x4 v; } pk;
#pragma unroll
    for (int j = 0; j < 8; ++j) {
        int ci = c * 8 + j;
        pk.s[j] = f2bf(x[((b * CI + ci) * HH + h) * WW + w]);
    }
    *(u32x4*)(xT + (((b * HH + h) * WW + w) * CI + c * 8)) = pk.v;
}

// ---------------- kernel 3: LDS-free implicit-GEMM conv ----------------
// Block: (hp, b), 256 thr = 4 waves, output 64co x 256pix (2 rows).
// Wave (wv): row_local = wv>>1, wbase = (wv&1)*64. Per wave: m=2 x n=2 frags.
// B straight from xT (L1/L2); A straight from aggw (L2). No LDS, no barriers.
__device__ __forceinline__ bf16x8 loadB(const char* base, int voff, bool valid) {
    u32x4 u = *(const u32x4*)(base + voff);
    if (!valid) u = u32x4{0u, 0u, 0u, 0u};
    union { u32x4 u; bf16x8 v; } cv; cv.u = u;
    return cv.v;
}

__global__ __launch_bounds__(256, 3) void conv_kernel(const short* __restrict__ xT,
                                                      const short* __restrict__ aggw,
                                                      const float* __restrict__ aggb,
                                                      float* __restrict__ out) {
    const int t  = threadIdx.x;
    // XCD-chunked swizzle: consecutive hp land on the same XCD (halo-row L2 reuse)
    const int bx = blockIdx.x;
    const int hp = (bx & 7) * 8 + (bx >> 3);           // bijective on 64
    const int b  = blockIdx.y;
    const int h0 = hp * 2;

    const int l  = t & 63;
    const int wv = t >> 6;                 // 0..3
    const int lm = l & 31;                 // m/n lane index
    const int g  = l >> 5;                 // k lane-group
    const int row_local = wv >> 1;         // 0..1
    const int wbase = (wv & 1) * 64;       // 0 or 64

    // ---- A addressing: aggw_b + (m*32+lm)*1152B + g*16B, imm = tap*128 + q*32
    const char* aggw_b = (const char*)(aggw + (size_t)b * CO * KDIM);
    int avoff[2];
#pragma unroll
    for (int m = 0; m < 2; ++m) avoff[m] = (m * 32 + lm) * (KDIM * 2) + g * 16;

    // ---- B addressing: xT_b + ((row)*128 + w)*128B ; row stride 16384B
    const char* xT_b = (const char*)(xT + (size_t)b * HH * WW * CI);
    int pix[2], voffL[2], voffM[2], voffR[2];
    bool mskL[2], mskR[2];
#pragma unroll
    for (int n = 0; n < 2; ++n) {
        pix[n] = wbase + n * 32 + lm;                        // output w, 0..127
        int rb = (h0 + row_local - 1) * WW;                  // base input row index*W
        int wl = pix[n] - 1; if (wl < 0) wl = 0;
        int wr = pix[n] + 1; if (wr > 127) wr = 127;
        voffL[n] = (rb + wl)      * 128 + g * 16;
        voffM[n] = (rb + pix[n])  * 128 + g * 16;
        voffR[n] = (rb + wr)      * 128 + g * 16;
        mskL[n] = (pix[n] >= 1);
        mskR[n] = (pix[n] <= 126);
    }

    f32x16 acc[2][2];
#pragma unroll
    for (int m = 0; m < 2; ++m)
#pragma unroll
        for (int n = 0; n < 2; ++n)
            acc[m][n] = (f32x16)0.0f;

#pragma unroll
    for (int tap = 0; tap < 9; ++tap) {
        const int dy = tap / 3;
        const int dx = tap - dy * 3;
        const int hr = h0 + row_local + dy - 1;        // wave-uniform
        if ((unsigned)hr < 128u) {
            // A fragments: k = tap*64 + q*16 + g*8 + j
            bf16x8 a[2][4];
#pragma unroll
            for (int m = 0; m < 2; ++m)
#pragma unroll
                for (int q = 0; q < 4; ++q)
                    a[m][q] = *(const bf16x8*)(aggw_b + avoff[m] + tap * 128 + q * 32);

            const int dyoff = dy * (WW * 128);         // bytes per input row
#pragma unroll
            for (int q = 0; q < 4; ++q) {
                bf16x8 bb[2];
#pragma unroll
                for (int n = 0; n < 2; ++n) {
                    if (dx == 0)      bb[n] = loadB(xT_b + voffL[n] + dyoff, q * 32, mskL[n]);
                    else if (dx == 1) bb[n] = loadB(xT_b + voffM[n] + dyoff, q * 32, true);
                    else              bb[n] = loadB(xT_b + voffR[n] + dyoff, q * 32, mskR[n]);
                }
#pragma unroll
                for (int m = 0; m < 2; ++m)
#pragma unroll
                    for (int n = 0; n < 2; ++n)
                        acc[m][n] = __builtin_amdgcn_mfma_f32_32x32x16_bf16(a[m][q], bb[n], acc[m][n], 0, 0, 0);
            }
        }
    }

    // ---- epilogue: D[row][col]: col = lane&31, row = (rg&3) + 8*(rg>>2) + 4*g ----
    const int hrow = h0 + row_local;
#pragma unroll
    for (int m = 0; m < 2; ++m) {
#pragma unroll
        for (int n = 0; n < 2; ++n) {
            f32x16 v = acc[m][n];
            int wc = wbase + n * 32 + lm;
#pragma unroll
            for (int rg = 0; rg < 16; ++rg) {
                int rowd = (rg & 3) + 8 * (rg >> 2) + 4 * g;
                int co = m * 32 + rowd;
                out[(((size_t)b * CO + co) * HH + hrow) * WW + wc] = v[rg] + aggb[b * CO + co];
            }
        }
    }
}

extern "C" void kernel_launch(void* const* d_in, const int* in_sizes, int n_in,
                              void* d_out, int out_size, void* d_ws, size_t ws_size,
                              hipStream_t stream) {
    const float* x       = (const float*)d_in[0];
    const float* weights = (const float*)d_in[1];
    const float* Wbank   = (const float*)d_in[2];
    const float* bbank   = (const float*)d_in[3];
    float* out = (float*)d_out;

    short* xT   = (short*)d_ws;                                  // 33,554,432 B
    short* aggw = (short*)((char*)d_ws + 33554432);              //  1,179,648 B
    float* aggb = (float*)((char*)d_ws + 34734080);              //      4,096 B

    prep_kernel<<<dim3((NB * CO * KDIM) / 256), dim3(256), 0, stream>>>(weights, Wbank, bbank, aggw, aggb);
    transpose_kernel<<<dim3((NB * HH * WW * CI / 8) / 256), dim3(256), 0, stream>>>(x, xT);
    conv_kernel<<<dim3(64, NB), dim3(256), 0, stream>>>(xT, aggw, aggb, out);
}

// Round 4
// 64.967 us; speedup vs baseline: 1.6938x; 1.6938x over previous
//
#include <hip/hip_runtime.h>
#include <hip/hip_bf16.h>

// Dynamic conv2d: B=16, C_in=64, H=W=128, C_out=64, K=5, ks=3, pad=1.
// R4: fused conv — read fp32 x directly, cvt+transpose into a rolling 3-row
// LDS ring (reg-staged, T14 split), MFMA 32x32x16 bf16. No transpose pass.

typedef __attribute__((ext_vector_type(8))) __bf16 bf16x8;
typedef __attribute__((ext_vector_type(16))) float f32x16;
typedef __attribute__((ext_vector_type(2))) unsigned int u32x2;
typedef __attribute__((ext_vector_type(4))) unsigned int u32x4;

#define NB 16
#define CI 64
#define CO 64
#define HH 128
#define WW 128
#define KBANK 5
#define KDIM 576              // CI*9, k = tap*64 + ci
#define PITCH 72              // shorts per pixel row (64 data + 8 pad -> 144B pitch)
#define BUFS (130 * PITCH)    // shorts per row buffer (9360)

__device__ __forceinline__ unsigned short f2bfu(float f) {
    __hip_bfloat16 h = __float2bfloat16(f);
    unsigned short s;
    __builtin_memcpy(&s, &h, 2);
    return s;
}

// ---------------- kernel 1: aggregate weights + bias ----------------
__global__ void prep_kernel(const float* __restrict__ weights,
                            const float* __restrict__ Wbank,
                            const float* __restrict__ bbank,
                            short* __restrict__ aggw,
                            float* __restrict__ aggb) {
    int idx = blockIdx.x * 256 + threadIdx.x;          // < 16*64*576
    int b  = idx / (CO * KDIM);
    int r  = idx - b * (CO * KDIM);
    int co = r / KDIM;
    int k  = r - co * KDIM;
    int tap = k >> 6;
    int ci  = k & 63;
    float s = 0.f;
#pragma unroll
    for (int kk = 0; kk < KBANK; ++kk)
        s += weights[b * KBANK + kk] * Wbank[((kk * CO + co) * CI + ci) * 9 + tap];
    aggw[idx] = (short)f2bfu(s);
    if (k == 0) {
        float sb = 0.f;
#pragma unroll
        for (int kk = 0; kk < KBANK; ++kk)
            sb += weights[b * KBANK + kk] * bbank[kk * CO + co];
        aggb[b * CO + co] = sb;
    }
}

// ---------------- kernel 2: fused rolling conv ----------------
// Block: 512 thr = 8 waves; 4 output rows x 64 co x 128 pix.
// Ring: 3 row-buffers [130 pix][72 shorts]; pix 0/129 pre-zeroed (padding).
__device__ __forceinline__ void load16(const float* __restrict__ xb, int r,
                                       int sw, int scg, float pv[16]) {
#pragma unroll
    for (int rr = 0; rr < 4; ++rr) {
        int ci0 = (rr * 4 + scg) * 4;
#pragma unroll
        for (int k = 0; k < 4; ++k)
            pv[rr * 4 + k] = xb[((size_t)(ci0 + k) * HH + r) * WW + sw];
    }
}

__device__ __forceinline__ void write16(short* __restrict__ nb, int sw, int scg,
                                        const float pv[16]) {
#pragma unroll
    for (int rr = 0; rr < 4; ++rr) {
        int ci0 = (rr * 4 + scg) * 4;
        unsigned int u0 = (unsigned)f2bfu(pv[rr * 4 + 0]) | ((unsigned)f2bfu(pv[rr * 4 + 1]) << 16);
        unsigned int u1 = (unsigned)f2bfu(pv[rr * 4 + 2]) | ((unsigned)f2bfu(pv[rr * 4 + 3]) << 16);
        *(u32x2*)&nb[(sw + 1) * PITCH + (ci0 >> 3) * 8 + (ci0 & 7)] = u32x2{u0, u1};
    }
}

__global__ __launch_bounds__(512, 4) void conv_kernel(const float* __restrict__ x,
                                                      const short* __restrict__ aggw,
                                                      const float* __restrict__ aggb,
                                                      float* __restrict__ out) {
    __shared__ short ring[3 * BUFS];                   // 56,160 B

    const int t = threadIdx.x;
    // XCD swizzle: all 32 row-blocks of a given b land on one XCD (halo L2 reuse)
    int lin = blockIdx.y * 32 + blockIdx.x;            // 0..511
    lin = ((lin & 7) << 6) | (lin >> 3);               // bijective
    const int hq = lin & 31;
    const int b  = lin >> 5;
    const int h0 = hq * 4;

    const int l    = t & 63;
    const int wv   = t >> 6;       // 0..7
    const int lm   = l & 31;
    const int g    = l >> 5;
    const int rl   = wv >> 1;      // output row 0..3 within block
    const int half = wv & 1;       // pix half

    const int sw  = t & 127;       // staging: w
    const int scg = t >> 7;        // staging: ci group 0..3

    const float* xb = x + (size_t)b * CI * HH * WW;
    const short* Aw = aggw + ((size_t)b * CO + lm) * KDIM;

    // pre-zero halo pixels (pix 0 and 129) of all 3 buffers — staging never
    // touches them, so they stay zero (left/right zero padding).
    if (t < 48) {
        int bi = t >> 4, c = t & 15;
        int pix = (c >> 3) * 129, ch = c & 7;
        *(u32x4*)&ring[bi * BUFS + pix * PITCH + ch * 8] = u32x4{0u, 0u, 0u, 0u};
    }

    // prologue: stage row h0-1 into buf 0 (skip if out of range)
    {
        float pv[16];
        if (h0 >= 1) {
            load16(xb, h0 - 1, sw, scg, pv);
            write16(&ring[0], sw, scg, pv);            // auto vmcnt wait
        }
    }
    asm volatile("s_waitcnt lgkmcnt(0)" ::: "memory");
    __builtin_amdgcn_s_barrier();
    __builtin_amdgcn_sched_barrier(0);

    f32x16 acc[2][2];
#pragma unroll
    for (int m = 0; m < 2; ++m)
#pragma unroll
        for (int n = 0; n < 2; ++n)
            acc[m][n] = (f32x16)0.0f;

    for (int s = 0; s < 6; ++s) {
        const int r  = h0 - 1 + s;                     // input row this step
        const int dy = s - rl;                         // this wave's tap row
        const bool active  = (dy >= 0) && (dy <= 2) && ((unsigned)r < 128u);
        const bool do_pref = (s < 5) && (h0 + s < 128);
        const short* cb = &ring[(s % 3) * BUFS];
        short*       nb = &ring[((s + 1) % 3) * BUFS];

        float pv[16];
        if (active) {
            const int tb = dy * 3;
#pragma unroll
            for (int dx = 0; dx < 3; ++dx) {
                if (dx == 2 && do_pref)
                    load16(xb, h0 + s, sw, scg, pv);   // issue late: avoid poisoning A-waits
                const int tap = tb + dx;
#pragma unroll
                for (int q = 0; q < 4; ++q) {
                    bf16x8 a0 = *(const bf16x8*)(Aw + 0 * 32 * KDIM + tap * 64 + q * 16 + g * 8);
                    bf16x8 a1 = *(const bf16x8*)(Aw + 1 * 32 * KDIM + tap * 64 + q * 16 + g * 8);
                    const int p0 = half * 64 + lm + dx;
                    bf16x8 b0 = *(const bf16x8*)&cb[p0 * PITCH + (q * 2 + g) * 8];
                    bf16x8 b1 = *(const bf16x8*)&cb[(p0 + 32) * PITCH + (q * 2 + g) * 8];
                    acc[0][0] = __builtin_amdgcn_mfma_f32_32x32x16_bf16(a0, b0, acc[0][0], 0, 0, 0);
                    acc[0][1] = __builtin_amdgcn_mfma_f32_32x32x16_bf16(a0, b1, acc[0][1], 0, 0, 0);
                    acc[1][0] = __builtin_amdgcn_mfma_f32_32x32x16_bf16(a1, b0, acc[1][0], 0, 0, 0);
                    acc[1][1] = __builtin_amdgcn_mfma_f32_32x32x16_bf16(a1, b1, acc[1][1], 0, 0, 0);
                }
            }
        } else if (do_pref) {
            load16(xb, h0 + s, sw, scg, pv);
        }
        if (do_pref)
            write16(nb, sw, scg, pv);                  // auto vmcnt wait on pv loads

        asm volatile("s_waitcnt lgkmcnt(0)" ::: "memory");
        __builtin_amdgcn_s_barrier();
        __builtin_amdgcn_sched_barrier(0);
    }

    // epilogue: D col = lane&31, row = (rg&3) + 8*(rg>>2) + 4*g
    const int hrow = h0 + rl;
#pragma unroll
    for (int m = 0; m < 2; ++m) {
#pragma unroll
        for (int n = 0; n < 2; ++n) {
            const int wc = half * 64 + n * 32 + lm;
#pragma unroll
            for (int rg = 0; rg < 16; ++rg) {
                int co = m * 32 + (rg & 3) + 8 * (rg >> 2) + 4 * g;
                out[(((size_t)b * CO + co) * HH + hrow) * WW + wc] = acc[m][n][rg] + aggb[b * CO + co];
            }
        }
    }
}

extern "C" void kernel_launch(void* const* d_in, const int* in_sizes, int n_in,
                              void* d_out, int out_size, void* d_ws, size_t ws_size,
                              hipStream_t stream) {
    const float* x       = (const float*)d_in[0];
    const float* weights = (const float*)d_in[1];
    const float* Wbank   = (const float*)d_in[2];
    const float* bbank   = (const float*)d_in[3];
    float* out = (float*)d_out;

    short* aggw = (short*)d_ws;                          // 1,179,648 B
    float* aggb = (float*)((char*)d_ws + 1179648);       //     4,096 B

    prep_kernel<<<dim3((NB * CO * KDIM) / 256), dim3(256), 0, stream>>>(weights, Wbank, bbank, aggw, aggb);
    conv_kernel<<<dim3(32, NB), dim3(512), 0, stream>>>(x, aggw, aggb, out);
}